// Round 11
// baseline (2667.334 us; speedup 1.0000x reference)
//
#include <hip/hip_runtime.h>
#include <hip/hip_bf16.h>
#include <math.h>

// B=64, S=128, V=50257, E=1024, H=1024, G=3H=3072
#define GRU_B 64
#define GRU_S 128
#define GRU_E 1024
#define GRU_H 1024
#define GRU_G 3072

#define SENT 0xFFFFFFFFFFFFFFFFull

typedef _Float16 half8 __attribute__((ext_vector_type(8)));
typedef _Float16 half4v __attribute__((ext_vector_type(4)));
typedef float floatx4 __attribute__((ext_vector_type(4)));
typedef unsigned long long ull2 __attribute__((ext_vector_type(2)));

__device__ __forceinline__ half8 cvt_h8(float4 a, float4 b) {
    half8 r;
    r[0] = (_Float16)a.x; r[1] = (_Float16)a.y;
    r[2] = (_Float16)a.z; r[3] = (_Float16)a.w;
    r[4] = (_Float16)b.x; r[5] = (_Float16)b.y;
    r[6] = (_Float16)b.z; r[7] = (_Float16)b.w;
    return r;
}

// ---------------------------------------------------------------------------
// Phase 1 (unchanged, proven): x_proj = emb[tok] @ w_ih^T + b_ih, fp16 MFMA.
// ---------------------------------------------------------------------------
__global__ __launch_bounds__(256) void xproj_mfma(
    const int* __restrict__ tokens,     // [B][S]
    const float* __restrict__ emb,      // [V][E]
    const float* __restrict__ w_ih,     // [G][E]
    const float* __restrict__ b_ih,     // [G]
    float* __restrict__ xproj)          // [M][G], m = s*64+b
{
    __shared__ __attribute__((aligned(16))) _Float16 Al[128 * 32];
    __shared__ __attribute__((aligned(16))) _Float16 Bl[128 * 32];
    __shared__ int toks[128];

    const int t  = threadIdx.x;
    const int m0 = blockIdx.x * 128;
    const int n0 = blockIdx.y * 128;

    if (t < 128) {
        int m = m0 + t;
        toks[t] = tokens[(m & 63) * GRU_S + (m >> 6)];   // tokens[b][s]
    }

    const int wid = t >> 6;
    const int l   = t & 63;
    const int wm  = (wid >> 1) * 64;
    const int wn  = (wid & 1) * 64;

    const int sr   = t >> 1;
    const int skw  = (sr >> 1) & 3;
    const int gb   = (t & 1) * 2;

    const int fr   = l & 15;
    const int ag   = l >> 4;
    const int skey = (fr >> 1) & 3;
    const int gfr  = (ag ^ skey) * 16;

    char* ab = reinterpret_cast<char*>(Al);
    char* bb = reinterpret_cast<char*>(Bl);

    floatx4 acc[4][4];
#pragma unroll
    for (int i = 0; i < 4; ++i)
#pragma unroll
        for (int j = 0; j < 4; ++j)
            acc[i][j] = (floatx4){0.f, 0.f, 0.f, 0.f};

    for (int k0 = 0; k0 < GRU_E; k0 += 32) {
        __syncthreads();
        {
            const float4* asrc = reinterpret_cast<const float4*>(
                emb + (size_t)toks[sr] * GRU_E + k0 + (t & 1) * 16);
            const float4* bsrc = reinterpret_cast<const float4*>(
                w_ih + (size_t)(n0 + sr) * GRU_E + k0 + (t & 1) * 16);
            float4 a0 = asrc[0], a1 = asrc[1], a2 = asrc[2], a3 = asrc[3];
            float4 b0 = bsrc[0], b1 = bsrc[1], b2 = bsrc[2], b3 = bsrc[3];
            *reinterpret_cast<half8*>(ab + sr * 64 + ((gb + 0) ^ skw) * 16) = cvt_h8(a0, a1);
            *reinterpret_cast<half8*>(ab + sr * 64 + ((gb + 1) ^ skw) * 16) = cvt_h8(a2, a3);
            *reinterpret_cast<half8*>(bb + sr * 64 + ((gb + 0) ^ skw) * 16) = cvt_h8(b0, b1);
            *reinterpret_cast<half8*>(bb + sr * 64 + ((gb + 1) ^ skw) * 16) = cvt_h8(b2, b3);
        }
        __syncthreads();

        half8 a4[4], b4[4];
#pragma unroll
        for (int mi = 0; mi < 4; ++mi)
            a4[mi] = *reinterpret_cast<const half8*>(ab + (wm + mi * 16 + fr) * 64 + gfr);
#pragma unroll
        for (int ni = 0; ni < 4; ++ni)
            b4[ni] = *reinterpret_cast<const half8*>(bb + (wn + ni * 16 + fr) * 64 + gfr);
#pragma unroll
        for (int mi = 0; mi < 4; ++mi)
#pragma unroll
            for (int ni = 0; ni < 4; ++ni)
                acc[mi][ni] = __builtin_amdgcn_mfma_f32_16x16x32_f16(
                    a4[mi], b4[ni], acc[mi][ni], 0, 0, 0);
    }

    const int cr = (l >> 4) * 4;
    const int cc = l & 15;
#pragma unroll
    for (int ni = 0; ni < 4; ++ni) {
        int n = n0 + wn + ni * 16 + cc;
        float bias = b_ih[n];
#pragma unroll
        for (int mi = 0; mi < 4; ++mi) {
#pragma unroll
            for (int q = 0; q < 4; ++q) {
                int m = m0 + wm + mi * 16 + cr + q;
                xproj[(size_t)m * GRU_G + n] = acc[mi][ni][q] + bias;
            }
        }
    }
}

// ---------------------------------------------------------------------------
// Phase 2: persistent GRU, DATA-AS-FLAG sentinel protocol. No flags, no
// fences, no cache maintenance.
//   ring:   3 h-buffers. iter s: read buf[s%3]; sentinel own quads of
//           buf[(s+2)%3]; vmcnt(0); swap h[s+1] into buf[(s+1)%3].
//   writes: returnless global_atomic_swap_x2 (agent) -> visible at IF (R8).
//   reads:  __hip_atomic_load SYSTEM-scope 8B, spin until != SENT (R8/R10).
//   SENT = 0xFF..FF (fp16 -NaN x4) is unreachable: every stored h is finite.
//   Waves fully independent (R10-proven topology): wave wid reads/writes
//   only batch rows wid*16..+15. No __syncthreads in the loop.
//   Init: host memset buf0=0 (=h0, instantly valid), buf1/2=0xFF.
// ---------------------------------------------------------------------------
__global__ __launch_bounds__(256) void gru_persist(
    const float* __restrict__ xproj,    // [S][B][G]
    const float* __restrict__ w_hh,     // [G][H]
    const float* __restrict__ b_hh,     // [G]
    _Float16* __restrict__ hb3,         // 3 x [64][1024] fp16 (memset by host)
    float* __restrict__ out)            // [64][1024]
{
    __shared__ __attribute__((aligned(16))) _Float16 wlds[48 * 1024];  // 96 KB

    const int t   = threadIdx.x;
    const int jb  = blockIdx.x;         // 0..63
    const int l   = t & 63;
    const int wid = t >> 6;
    const int m0  = wid * 16;

    // ---- stage W: 48 rows (gate*16+jloc), fp32 -> fp16, swizzled ----
    {
        char* wbp = reinterpret_cast<char*>(wlds);
        for (int r = 0; r < 48; ++r) {
            int grow = (r >> 4) * GRU_H + jb * 16 + (r & 15);
            float4 v = reinterpret_cast<const float4*>(
                w_hh + (size_t)grow * GRU_H)[t];
            half4v hv;
            hv.x = (_Float16)v.x; hv.y = (_Float16)v.y;
            hv.z = (_Float16)v.z; hv.w = (_Float16)v.w;
            int g = (t >> 1) ^ (r & 7);
            *reinterpret_cast<half4v*>(wbp + r * 2048 + g * 16 + (t & 1) * 8) = hv;
        }
    }
    __syncthreads();   // W staged (only barrier in the kernel)

    // ---- per-thread constants ----
    const int jl   = l & 15;
    const int qrow = (l >> 4) * 4;
    const int j    = jb * 16 + jl;
    const float bhr = b_hh[j];
    const float bhz = b_hh[GRU_H + j];
    const float bhn = b_hh[2 * GRU_H + j];

    const int arow   = m0 + (l & 15);        // A-frag h row
    const int aoff64 = (l >> 4) * 2;         // A-frag k offset in ull units
    const int sk     = jl & 7;
    const char* wb   = reinterpret_cast<const char*>(wlds);
    const int bbase0 = (0 * 16 + jl) * 2048;
    const int bbase1 = (1 * 16 + jl) * 2048;
    const int bbase2 = (2 * 16 + jl) * 2048;

    const int colq   = (jb * 16 + jl) >> 2;  // ull column (256 per row)
    const bool leader = ((l & 3) == 0);

    float hp[4] = {0.f, 0.f, 0.f, 0.f};
    float xr[4], xz[4], xnn[4];

    // prefetch x_proj for step 0 (plain cached loads; L2 stays warm forever)
#pragma unroll
    for (int q = 0; q < 4; ++q) {
        const float* row = xproj + (size_t)(m0 + qrow + q) * GRU_G;
        xr[q]  = row[j];
        xz[q]  = row[GRU_H + j];
        xnn[q] = row[2 * GRU_H + j];
    }

    const size_t BUFQ = (size_t)GRU_B * GRU_H / 4;   // 16384 ull per buffer

    for (int s = 0; s < GRU_S; ++s) {
        unsigned long long* base =
            reinterpret_cast<unsigned long long*>(hb3);
        const unsigned long long* rb = base + (size_t)(s % 3) * BUFQ;
        unsigned long long* wbuf     = base + (size_t)((s + 1) % 3) * BUFQ;
        unsigned long long* sbuf     = base + (size_t)((s + 2) % 3) * BUFQ;

        // ---- spin-read this lane's A slice: data-as-flag ----
        const unsigned long long* abase = rb + (size_t)arow * 256 + aoff64;
        unsigned long long a0[32], a1[32];
        while (true) {
            unsigned int ok = 1u;
#pragma unroll
            for (int kc = 0; kc < 32; ++kc) {
                a0[kc] = __hip_atomic_load(abase + kc * 8,
                    __ATOMIC_RELAXED, __HIP_MEMORY_SCOPE_SYSTEM);
                a1[kc] = __hip_atomic_load(abase + kc * 8 + 1,
                    __ATOMIC_RELAXED, __HIP_MEMORY_SCOPE_SYSTEM);
            }
#pragma unroll
            for (int kc = 0; kc < 32; ++kc)
                ok &= (unsigned int)(a0[kc] != SENT) &
                      (unsigned int)(a1[kc] != SENT);
            if (__all(ok)) break;
        }
        asm volatile("" ::: "memory");

        // ---- sentinel own quads of buf[(s+2)%3] (readers provably done);
        //      flies during MFMA, ordered before publish by the vmcnt below.
        if (s < GRU_S - 2) {
#pragma unroll
            for (int q = 0; q < 4; ++q)
                if (leader)
                    (void)__hip_atomic_exchange(
                        sbuf + (size_t)(m0 + qrow + q) * 256 + colq, SENT,
                        __ATOMIC_RELAXED, __HIP_MEMORY_SCOPE_AGENT);
        }

        // ---- MFMA: 64x48x1024 from registers (A) and LDS (B) ----
        floatx4 acc0 = {0.f, 0.f, 0.f, 0.f};
        floatx4 acc1 = {0.f, 0.f, 0.f, 0.f};
        floatx4 acc2 = {0.f, 0.f, 0.f, 0.f};

#pragma unroll 8
        for (int kc = 0; kc < 32; ++kc) {
            ull2 tmp; tmp.x = a0[kc]; tmp.y = a1[kc];
            half8 a = __builtin_bit_cast(half8, tmp);
            int g = (kc * 4 + (l >> 4)) ^ sk;
            half8 b0 = *reinterpret_cast<const half8*>(wb + bbase0 + g * 16);
            half8 b1 = *reinterpret_cast<const half8*>(wb + bbase1 + g * 16);
            half8 b2 = *reinterpret_cast<const half8*>(wb + bbase2 + g * 16);
            acc0 = __builtin_amdgcn_mfma_f32_16x16x32_f16(a, b0, acc0, 0, 0, 0);
            acc1 = __builtin_amdgcn_mfma_f32_16x16x32_f16(a, b1, acc1, 0, 0, 0);
            acc2 = __builtin_amdgcn_mfma_f32_16x16x32_f16(a, b2, acc2, 0, 0, 0);
        }

        const bool last = (s == GRU_S - 1);

        // ---- fused gate epilogue ----
        unsigned int dw[4];
#pragma unroll
        for (int q = 0; q < 4; ++q) {
            float r  = 1.f / (1.f + __expf(-(xr[q] + acc0[q] + bhr)));
            float zg = 1.f / (1.f + __expf(-(xz[q] + acc1[q] + bhz)));
            float pre = xnn[q] + r * (acc2[q] + bhn);
            pre = fminf(fmaxf(pre, -15.f), 15.f);
            float e2 = __expf(2.f * pre);
            float ng = (e2 - 1.f) / (e2 + 1.f);
            float h  = (1.f - zg) * ng + zg * hp[q];
            hp[q] = h;
            unsigned int hu = (unsigned int)__builtin_bit_cast(
                unsigned short, (_Float16)h);
            unsigned int ot = (unsigned int)__shfl_xor((int)hu, 1);
            dw[q] = hu | (ot << 16);
        }

        if (!last) {
            // order: sentinels (and everything else) at IF BEFORE publish
            asm volatile("s_waitcnt vmcnt(0)" ::: "memory");
            __builtin_amdgcn_sched_barrier(0);

            // publish h[s+1]: quad-pack on 4-lane leaders, swap to IF
#pragma unroll
            for (int q = 0; q < 4; ++q) {
                unsigned int hi = (unsigned int)__shfl_xor((int)dw[q], 2);
                if (leader) {
                    unsigned long long qw =
                        (unsigned long long)dw[q] |
                        ((unsigned long long)hi << 32);
                    (void)__hip_atomic_exchange(
                        wbuf + (size_t)(m0 + qrow + q) * 256 + colq, qw,
                        __ATOMIC_RELAXED, __HIP_MEMORY_SCOPE_AGENT);
                }
            }

            // prefetch x_proj for s+1 (flies during next spin)
            const float* xpS = xproj + (size_t)(s + 1) * (GRU_B * GRU_G);
#pragma unroll
            for (int q = 0; q < 4; ++q) {
                const float* row = xpS + (size_t)(m0 + qrow + q) * GRU_G;
                xr[q]  = row[j];
                xz[q]  = row[GRU_H + j];
                xnn[q] = row[2 * GRU_H + j];
            }
        }
    }

    // final hidden state -> output (fp32, plain stores)
#pragma unroll
    for (int q = 0; q < 4; ++q)
        out[(size_t)(m0 + qrow + q) * GRU_H + j] = hp[q];
}

// ---------------------------------------------------------------------------
// Launch
// ---------------------------------------------------------------------------
extern "C" void kernel_launch(void* const* d_in, const int* in_sizes, int n_in,
                              void* d_out, int out_size, void* d_ws, size_t ws_size,
                              hipStream_t stream) {
    const int*   tokens = (const int*)  d_in[0];
    const float* emb    = (const float*)d_in[1];
    const float* w_ih   = (const float*)d_in[2];
    const float* w_hh   = (const float*)d_in[3];
    const float* b_ih   = (const float*)d_in[4];
    const float* b_hh   = (const float*)d_in[5];
    float* out = (float*)d_out;

    float*    xproj = (float*)d_ws;                                       // 96 MB
    _Float16* hb3   = (_Float16*)(xproj + (size_t)GRU_S * GRU_B * GRU_G); // 384 KB

    const size_t BUFB = (size_t)GRU_B * GRU_H * sizeof(_Float16);  // 128 KB

    // buf0 = h(0) = 0 (valid data); buf1, buf2 = sentinel 0xFF..FF
    hipMemsetAsync(hb3, 0, BUFB, stream);
    hipMemsetAsync((char*)hb3 + BUFB, 0xFF, 2 * BUFB, stream);

    {
        dim3 grid(GRU_B * GRU_S / 128, GRU_G / 128);   // 64 x 24
        xproj_mfma<<<grid, 256, 0, stream>>>(tokens, emb, w_ih, b_ih, xproj);
    }

    {
        const float* xp_a = xproj;
        const float* whh_a = w_hh;
        const float* bhh_a = b_hh;
        _Float16* hb_a = hb3;
        float* out_a = out;
        void* args[] = { (void*)&xp_a, (void*)&whh_a, (void*)&bhh_a,
                         (void*)&hb_a, (void*)&out_a };
        hipLaunchCooperativeKernel((void*)gru_persist, dim3(64), dim3(256),
                                   args, 0, stream);
    }
}

// Round 12
// 880.789 us; speedup vs baseline: 3.0283x; 3.0283x over previous
//
#include <hip/hip_runtime.h>
#include <hip/hip_bf16.h>
#include <math.h>

// B=64, S=128, V=50257, E=1024, H=1024, G=3H=3072
#define GRU_B 64
#define GRU_S 128
#define GRU_E 1024
#define GRU_H 1024
#define GRU_G 3072

typedef _Float16 half8 __attribute__((ext_vector_type(8)));
typedef _Float16 half4v __attribute__((ext_vector_type(4)));
typedef float floatx4 __attribute__((ext_vector_type(4)));

__device__ __forceinline__ half8 cvt_h8(float4 a, float4 b) {
    half8 r;
    r[0] = (_Float16)a.x; r[1] = (_Float16)a.y;
    r[2] = (_Float16)a.z; r[3] = (_Float16)a.w;
    r[4] = (_Float16)b.x; r[5] = (_Float16)b.y;
    r[6] = (_Float16)b.z; r[7] = (_Float16)b.w;
    return r;
}

// ---------------------------------------------------------------------------
// Phase 1: x_proj = emb[tok] @ w_ih^T + b_ih, fp16 MFMA. Output now FP16
// (halves write traffic + shrinks ws so the h-ring fits the proven budget).
// ---------------------------------------------------------------------------
__global__ __launch_bounds__(256) void xproj_mfma(
    const int* __restrict__ tokens,     // [B][S]
    const float* __restrict__ emb,      // [V][E]
    const float* __restrict__ w_ih,     // [G][E]
    const float* __restrict__ b_ih,     // [G]
    _Float16* __restrict__ xproj)       // [M][G] fp16, m = s*64+b
{
    __shared__ __attribute__((aligned(16))) _Float16 Al[128 * 32];
    __shared__ __attribute__((aligned(16))) _Float16 Bl[128 * 32];
    __shared__ int toks[128];

    const int t  = threadIdx.x;
    const int m0 = blockIdx.x * 128;
    const int n0 = blockIdx.y * 128;

    if (t < 128) {
        int m = m0 + t;
        toks[t] = tokens[(m & 63) * GRU_S + (m >> 6)];   // tokens[b][s]
    }

    const int wid = t >> 6;
    const int l   = t & 63;
    const int wm  = (wid >> 1) * 64;
    const int wn  = (wid & 1) * 64;

    const int sr   = t >> 1;
    const int skw  = (sr >> 1) & 3;
    const int gb   = (t & 1) * 2;

    const int fr   = l & 15;
    const int ag   = l >> 4;
    const int skey = (fr >> 1) & 3;
    const int gfr  = (ag ^ skey) * 16;

    char* ab = reinterpret_cast<char*>(Al);
    char* bb = reinterpret_cast<char*>(Bl);

    floatx4 acc[4][4];
#pragma unroll
    for (int i = 0; i < 4; ++i)
#pragma unroll
        for (int j = 0; j < 4; ++j)
            acc[i][j] = (floatx4){0.f, 0.f, 0.f, 0.f};

    for (int k0 = 0; k0 < GRU_E; k0 += 32) {
        __syncthreads();
        {
            const float4* asrc = reinterpret_cast<const float4*>(
                emb + (size_t)toks[sr] * GRU_E + k0 + (t & 1) * 16);
            const float4* bsrc = reinterpret_cast<const float4*>(
                w_ih + (size_t)(n0 + sr) * GRU_E + k0 + (t & 1) * 16);
            float4 a0 = asrc[0], a1 = asrc[1], a2 = asrc[2], a3 = asrc[3];
            float4 b0 = bsrc[0], b1 = bsrc[1], b2 = bsrc[2], b3 = bsrc[3];
            *reinterpret_cast<half8*>(ab + sr * 64 + ((gb + 0) ^ skw) * 16) = cvt_h8(a0, a1);
            *reinterpret_cast<half8*>(ab + sr * 64 + ((gb + 1) ^ skw) * 16) = cvt_h8(a2, a3);
            *reinterpret_cast<half8*>(bb + sr * 64 + ((gb + 0) ^ skw) * 16) = cvt_h8(b0, b1);
            *reinterpret_cast<half8*>(bb + sr * 64 + ((gb + 1) ^ skw) * 16) = cvt_h8(b2, b3);
        }
        __syncthreads();

        half8 a4[4], b4[4];
#pragma unroll
        for (int mi = 0; mi < 4; ++mi)
            a4[mi] = *reinterpret_cast<const half8*>(ab + (wm + mi * 16 + fr) * 64 + gfr);
#pragma unroll
        for (int ni = 0; ni < 4; ++ni)
            b4[ni] = *reinterpret_cast<const half8*>(bb + (wn + ni * 16 + fr) * 64 + gfr);
#pragma unroll
        for (int mi = 0; mi < 4; ++mi)
#pragma unroll
            for (int ni = 0; ni < 4; ++ni)
                acc[mi][ni] = __builtin_amdgcn_mfma_f32_16x16x32_f16(
                    a4[mi], b4[ni], acc[mi][ni], 0, 0, 0);
    }

    const int cr = (l >> 4) * 4;
    const int cc = l & 15;
#pragma unroll
    for (int ni = 0; ni < 4; ++ni) {
        int n = n0 + wn + ni * 16 + cc;
        float bias = b_ih[n];
#pragma unroll
        for (int mi = 0; mi < 4; ++mi) {
#pragma unroll
            for (int q = 0; q < 4; ++q) {
                int m = m0 + wm + mi * 16 + cr + q;
                xproj[(size_t)m * GRU_G + n] = (_Float16)(acc[mi][ni][q] + bias);
            }
        }
    }
}

// ---------------------------------------------------------------------------
// Phase 2: persistent GRU, FRESH-REGION RING protocol.
//   ring:   128 buffers (one per step, 128 KB each), laid DESCENDING
//           (buffer for step s at slot 127-s) so prefetch-ahead from the
//           read stream lands in already-consumed buffers.
//   writes: returnless global_atomic_swap_x2 (agent) -> deposit at MALL/IF
//           [R8-proven]; per-wave drained by __syncthreads' vmcnt(0);
//           t0 stores flags[jb] (relaxed agent) [R8-proven].
//   reads:  PLAIN dwordx4 loads. Fresh addresses -> compulsory L1/L2 miss
//           -> line fetched from MALL (which holds the swap data). L2 lines
//           shared by the XCD's 8 blocks. No atomics, no fences in loop.
//   poison/replay-stale lines: ONE acquire fence (bulk inv) at kernel start.
// ---------------------------------------------------------------------------
__global__ __launch_bounds__(256) void gru_persist(
    const _Float16* __restrict__ xproj, // [S][B][G] fp16
    const float* __restrict__ w_hh,     // [G][H]
    const float* __restrict__ b_hh,     // [G]
    _Float16* __restrict__ ring,        // 128 x [64][1024] fp16
    float* __restrict__ out,            // [64][1024]
    int* __restrict__ flags)            // [64], zeroed by host
{
    __shared__ __attribute__((aligned(16))) _Float16 wlds[48 * 1024];  // 96 KB

    // one-time: drop any stale (poison / previous-replay) lines from this
    // XCD's caches. Inputs are clean-in-memory at kernel start (proven: R4/R7
    // fenced every step without corrupting them).
    __builtin_amdgcn_fence(__ATOMIC_ACQUIRE, "agent");

    const int t   = threadIdx.x;
    const int jb  = blockIdx.x;         // 0..63
    const int l   = t & 63;
    const int wid = t >> 6;
    const int m0  = wid * 16;

    const size_t BUFE = (size_t)GRU_B * GRU_H;       // halves per buffer
    const size_t BUFQ = BUFE / 4;                    // ulls per buffer

    // ---- stage W: 48 rows (gate*16+jloc), fp32 -> fp16, swizzled ----
    {
        char* wbp = reinterpret_cast<char*>(wlds);
        for (int r = 0; r < 48; ++r) {
            int grow = (r >> 4) * GRU_H + jb * 16 + (r & 15);
            float4 v = reinterpret_cast<const float4*>(
                w_hh + (size_t)grow * GRU_H)[t];
            half4v hv;
            hv.x = (_Float16)v.x; hv.y = (_Float16)v.y;
            hv.z = (_Float16)v.z; hv.w = (_Float16)v.w;
            int g = (t >> 1) ^ (r & 7);
            *reinterpret_cast<half4v*>(wbp + r * 2048 + g * 16 + (t & 1) * 8) = hv;
        }
    }

    // ---- zero h(0) = ring slot 127 via IF swaps (R8-proven init) ----
    {
        unsigned long long* z =
            reinterpret_cast<unsigned long long*>(ring) + 127 * BUFQ;
        int i0 = jb * 256 + t;          // 16384 ull
        (void)__hip_atomic_exchange(z + i0, 0ULL, __ATOMIC_RELAXED,
                                    __HIP_MEMORY_SCOPE_AGENT);
    }

    // ---- per-thread constants ----
    const int jl   = l & 15;
    const int qrow = (l >> 4) * 4;
    const int j    = jb * 16 + jl;
    const float bhr = b_hh[j];
    const float bhz = b_hh[GRU_H + j];
    const float bhn = b_hh[2 * GRU_H + j];

    const int arow  = m0 + (l & 15);         // A-frag h row
    const int akoff = (l >> 4) * 8;          // A-frag k offset (halves)
    const int sk    = jl & 7;
    const char* wb  = reinterpret_cast<const char*>(wlds);
    const int bbase0 = (0 * 16 + jl) * 2048;
    const int bbase1 = (1 * 16 + jl) * 2048;
    const int bbase2 = (2 * 16 + jl) * 2048;

    const int colq   = (jb * 16 + jl) >> 2;  // ull column (256 per row)
    const bool leader = ((l & 3) == 0);

    float hp[4] = {0.f, 0.f, 0.f, 0.f};
    float xr[4], xz[4], xnn[4];

    // ---- initial publish: zero-swaps acked at IF -> flag = 1 ----
    __syncthreads();                         // per-wave vmcnt(0) drains swaps
    if (t == 0)
        __hip_atomic_store(flags + jb, 1, __ATOMIC_RELAXED,
                           __HIP_MEMORY_SCOPE_AGENT);

    // prefetch x_proj (fp16) for step 0
#pragma unroll
    for (int q = 0; q < 4; ++q) {
        const _Float16* row = xproj + (size_t)(m0 + qrow + q) * GRU_G;
        xr[q]  = (float)row[j];
        xz[q]  = (float)row[GRU_H + j];
        xnn[q] = (float)row[2 * GRU_H + j];
    }

    for (int s = 0; s < GRU_S; ++s) {
        // ---- wait: all blocks published phase s+1 (wave0, calm poll) ----
        if (wid == 0) {
            const int tgt = s + 1;
            while (true) {
                int f = __hip_atomic_load(flags + l, __ATOMIC_RELAXED,
                                          __HIP_MEMORY_SCOPE_AGENT);
                if (__all(f >= tgt)) break;
                __builtin_amdgcn_s_sleep(1);
            }
        }
        __syncthreads();
        __builtin_amdgcn_sched_barrier(0);
        asm volatile("" ::: "memory");   // pin h loads after the poll

        // read h(s) from slot 127-s: fresh addresses -> compulsory miss
        const _Float16* hbuf = ring + (size_t)(127 - s) * BUFE;
        const _Float16* aptr = hbuf + (size_t)arow * GRU_H + akoff;

        floatx4 acc0 = {0.f, 0.f, 0.f, 0.f};
        floatx4 acc1 = {0.f, 0.f, 0.f, 0.f};
        floatx4 acc2 = {0.f, 0.f, 0.f, 0.f};

#pragma unroll 8
        for (int kc = 0; kc < 32; ++kc) {
            half8 a = *reinterpret_cast<const half8*>(aptr + kc * 32);
            int g = (kc * 4 + (l >> 4)) ^ sk;
            half8 b0 = *reinterpret_cast<const half8*>(wb + bbase0 + g * 16);
            half8 b1 = *reinterpret_cast<const half8*>(wb + bbase1 + g * 16);
            half8 b2 = *reinterpret_cast<const half8*>(wb + bbase2 + g * 16);
            acc0 = __builtin_amdgcn_mfma_f32_16x16x32_f16(a, b0, acc0, 0, 0, 0);
            acc1 = __builtin_amdgcn_mfma_f32_16x16x32_f16(a, b1, acc1, 0, 0, 0);
            acc2 = __builtin_amdgcn_mfma_f32_16x16x32_f16(a, b2, acc2, 0, 0, 0);
        }

        const bool last = (s == GRU_S - 1);

        // ---- fused gate epilogue ----
        unsigned int dw[4];
#pragma unroll
        for (int q = 0; q < 4; ++q) {
            float r  = 1.f / (1.f + __expf(-(xr[q] + acc0[q] + bhr)));
            float zg = 1.f / (1.f + __expf(-(xz[q] + acc1[q] + bhz)));
            float pre = xnn[q] + r * (acc2[q] + bhn);
            pre = fminf(fmaxf(pre, -15.f), 15.f);
            float e2 = __expf(2.f * pre);
            float ng = (e2 - 1.f) / (e2 + 1.f);
            float h  = (1.f - zg) * ng + zg * hp[q];
            hp[q] = h;
            unsigned int hu = (unsigned int)__builtin_bit_cast(
                unsigned short, (_Float16)h);
            unsigned int ot = (unsigned int)__shfl_xor((int)hu, 1);
            dw[q] = hu | (ot << 16);
        }

        if (!last) {
            // publish h(s+1) into FRESH slot 126-s (quad-pack swaps, proven)
            unsigned long long* wbuf =
                reinterpret_cast<unsigned long long*>(ring)
                + (size_t)(126 - s) * BUFQ;
#pragma unroll
            for (int q = 0; q < 4; ++q) {
                unsigned int hi = (unsigned int)__shfl_xor((int)dw[q], 2);
                if (leader) {
                    unsigned long long qw =
                        (unsigned long long)dw[q] |
                        ((unsigned long long)hi << 32);
                    (void)__hip_atomic_exchange(
                        wbuf + (size_t)(m0 + qrow + q) * 256 + colq, qw,
                        __ATOMIC_RELAXED, __HIP_MEMORY_SCOPE_AGENT);
                }
            }

            __syncthreads();             // per-wave vmcnt(0): swaps at IF
            if (t == 0)
                __hip_atomic_store(flags + jb, s + 2, __ATOMIC_RELAXED,
                                   __HIP_MEMORY_SCOPE_AGENT);
            asm volatile("" ::: "memory");

            // prefetch x_proj (fp16) for s+1 — flies during next poll
            const _Float16* xpS = xproj + (size_t)(s + 1) * (GRU_B * GRU_G);
#pragma unroll
            for (int q = 0; q < 4; ++q) {
                const _Float16* row = xpS + (size_t)(m0 + qrow + q) * GRU_G;
                xr[q]  = (float)row[j];
                xz[q]  = (float)row[GRU_H + j];
                xnn[q] = (float)row[2 * GRU_H + j];
            }
        }
    }

    // final hidden state -> output (fp32, plain stores)
#pragma unroll
    for (int q = 0; q < 4; ++q)
        out[(size_t)(m0 + qrow + q) * GRU_H + j] = hp[q];
}

// ---------------------------------------------------------------------------
// Launch
// ---------------------------------------------------------------------------
extern "C" void kernel_launch(void* const* d_in, const int* in_sizes, int n_in,
                              void* d_out, int out_size, void* d_ws, size_t ws_size,
                              hipStream_t stream) {
    const int*   tokens = (const int*)  d_in[0];
    const float* emb    = (const float*)d_in[1];
    const float* w_ih   = (const float*)d_in[2];
    const float* w_hh   = (const float*)d_in[3];
    const float* b_ih   = (const float*)d_in[4];
    const float* b_hh   = (const float*)d_in[5];
    float* out = (float*)d_out;

    // ws layout: xproj fp16 (50.3 MB) | ring 128x128KB (16.8 MB) | flags
    _Float16* xproj16 = (_Float16*)d_ws;
    _Float16* ring    = xproj16 + (size_t)GRU_S * GRU_B * GRU_G;
    int*      flags   = (int*)(ring + 128 * (size_t)GRU_B * GRU_H);

    hipMemsetAsync(flags, 0, 64 * sizeof(int), stream);

    {
        dim3 grid(GRU_B * GRU_S / 128, GRU_G / 128);   // 64 x 24
        xproj_mfma<<<grid, 256, 0, stream>>>(tokens, emb, w_ih, b_ih, xproj16);
    }

    {
        const _Float16* xp_a = xproj16;
        const float* whh_a = w_hh;
        const float* bhh_a = b_hh;
        _Float16* ring_a = ring;
        float* out_a = out;
        int* flags_a = flags;
        void* args[] = { (void*)&xp_a, (void*)&whh_a, (void*)&bhh_a,
                         (void*)&ring_a, (void*)&out_a, (void*)&flags_a };
        hipLaunchCooperativeKernel((void*)gru_persist, dim3(64), dim3(256),
                                   args, 0, stream);
    }
}